// Round 2
// baseline (2066.720 us; speedup 1.0000x reference)
//
#include <hip/hip_runtime.h>
#include <hip/hip_bf16.h>

#define N_B 4
#define N_H 16
#define T_S 2048
#define E_D 1024
#define H_D 64
#define Q_B 64
#define LP  72   // LDS row pitch in ushorts (144 B: 16B-aligned rows, ~2-way banks)

typedef __attribute__((ext_vector_type(8))) short bf16x8;
typedef __attribute__((ext_vector_type(4))) float f32x4;

__device__ __forceinline__ unsigned short bf_hi(float x) {
    return (unsigned short)(__float_as_uint(x) >> 16);
}
__device__ __forceinline__ float bf_hi_f(float x) {
    return __uint_as_float(__float_as_uint(x) & 0xFFFF0000u);
}
__device__ __forceinline__ unsigned short bf_rne(float x) {
    unsigned int b = __float_as_uint(x);
    b += 0x7FFFu + ((b >> 16) & 1u);
    return (unsigned short)(b >> 16);
}

// stage a 64x64 fp32 tile (row stride E_D) into hi/lo bf16 LDS tiles
__device__ __forceinline__ void stage_qk(unsigned short (*dh)[LP],
                                         unsigned short (*dl)[LP],
                                         const float* __restrict__ src,
                                         float scale, int tid) {
#pragma unroll
    for (int it = 0; it < 4; ++it) {
        int idx = tid + it * 256;          // 1024 float4s
        int r   = idx >> 4;
        int c   = (idx & 15) * 4;
        float4 v = *(const float4*)(src + (size_t)r * E_D + c);
        float x0 = v.x * scale, x1 = v.y * scale, x2 = v.z * scale, x3 = v.w * scale;
        uint2 hh, ll;
        hh.x = (unsigned)bf_hi(x0) | ((unsigned)bf_hi(x1) << 16);
        hh.y = (unsigned)bf_hi(x2) | ((unsigned)bf_hi(x3) << 16);
        ll.x = (unsigned)bf_rne(x0 - bf_hi_f(x0)) | ((unsigned)bf_rne(x1 - bf_hi_f(x1)) << 16);
        ll.y = (unsigned)bf_rne(x2 - bf_hi_f(x2)) | ((unsigned)bf_rne(x3 - bf_hi_f(x3)) << 16);
        *(uint2*)&dh[r][c] = hh;
        *(uint2*)&dl[r][c] = ll;
    }
}

__global__ __launch_bounds__(256, 3)
void mha_fused_kernel(const float* __restrict__ Qg,
                      const float* __restrict__ Kg,
                      const float* __restrict__ Vg,
                      float* __restrict__ Yg,
                      float* __restrict__ Ag) {
    __shared__ unsigned short Qh[Q_B][LP], Ql[Q_B][LP];
    __shared__ unsigned short KV0[64][LP], KV1[64][LP];   // K hi/lo (pass1), V^T hi/lo (pass2)
    __shared__ float mW[Q_B][32];
    __shared__ float mF[Q_B];
    __shared__ float iS[Q_B];

    const int tid  = threadIdx.x;
    const int lane = tid & 63;
    const int w    = tid >> 6;
    const int r16  = lane & 15;
    const int kg   = lane >> 4;

    const int b  = blockIdx.x;
    const int qb = b & 31;
    const int h  = (b >> 5) & 15;
    const int n  = b >> 9;
    const int q0 = qb * Q_B;

    const float* qbase = Qg + ((size_t)n * T_S + q0) * E_D + h * H_D;
    const float* kbase = Kg + (size_t)n * T_S * E_D + h * H_D;
    const float* vbase = Vg + (size_t)n * T_S * E_D + h * H_D;
    float* abase = Ag + (size_t)(n * N_H + h) * T_S * T_S;

    const float NINF = -__builtin_inff();

    // ---- stage Q (pre-scaled by 1/8, exact), hi/lo split ----
    stage_qk(Qh, Ql, qbase, 0.125f, tid);
    __syncthreads();

    // ---- Q fragments, held in registers across pass 1 ----
    // A layout (16x16x32): lane l -> row = l&15, k = (l>>4)*8 + e
    const int arow = w * 16 + r16;
    const bf16x8 qh0 = *(const bf16x8*)&Qh[arow][kg * 8];
    const bf16x8 qh1 = *(const bf16x8*)&Qh[arow][32 + kg * 8];
    const bf16x8 ql0 = *(const bf16x8*)&Ql[arow][kg * 8];
    const bf16x8 ql1 = *(const bf16x8*)&Ql[arow][32 + kg * 8];

    float m_run[4], s_run[4];
#pragma unroll
    for (int i = 0; i < 4; ++i) { m_run[i] = NINF; s_run[i] = 0.0f; }

    const int qrow_base = q0 + w * 16 + kg * 4;  // C layout: row=(l>>4)*4+i, col=l&15

    // ================= pass 1: scores + online softmax stats =================
    for (int cc = 0; cc <= qb; ++cc) {
        const int kc = cc * 64;
        __syncthreads();
        stage_qk(KV0, KV1, kbase + (size_t)kc * E_D, 1.0f, tid);
        __syncthreads();

        float sv[4][4];
#pragma unroll
        for (int t = 0; t < 4; ++t) {
            f32x4 acc = {0.f, 0.f, 0.f, 0.f};
            const int kr = t * 16 + r16;
            const bf16x8 kh0 = *(const bf16x8*)&KV0[kr][kg * 8];
            const bf16x8 kh1 = *(const bf16x8*)&KV0[kr][32 + kg * 8];
            const bf16x8 kl0 = *(const bf16x8*)&KV1[kr][kg * 8];
            const bf16x8 kl1 = *(const bf16x8*)&KV1[kr][32 + kg * 8];
            acc = __builtin_amdgcn_mfma_f32_16x16x32_bf16(qh0, kh0, acc, 0, 0, 0);
            acc = __builtin_amdgcn_mfma_f32_16x16x32_bf16(qh1, kh1, acc, 0, 0, 0);
            acc = __builtin_amdgcn_mfma_f32_16x16x32_bf16(qh0, kl0, acc, 0, 0, 0);
            acc = __builtin_amdgcn_mfma_f32_16x16x32_bf16(qh1, kl1, acc, 0, 0, 0);
            acc = __builtin_amdgcn_mfma_f32_16x16x32_bf16(ql0, kh0, acc, 0, 0, 0);
            acc = __builtin_amdgcn_mfma_f32_16x16x32_bf16(ql1, kh1, acc, 0, 0, 0);
#pragma unroll
            for (int i = 0; i < 4; ++i) sv[t][i] = acc[i];
        }

        // causal mask + row max
        float mt[4];
#pragma unroll
        for (int i = 0; i < 4; ++i) mt[i] = NINF;
#pragma unroll
        for (int t = 0; t < 4; ++t) {
            const int kgl = kc + t * 16 + r16;
#pragma unroll
            for (int i = 0; i < 4; ++i) {
                if (kgl > qrow_base + i) sv[t][i] = NINF;
                mt[i] = fmaxf(mt[i], sv[t][i]);
            }
        }
#pragma unroll
        for (int d = 1; d < 16; d <<= 1) {
#pragma unroll
            for (int i = 0; i < 4; ++i) mt[i] = fmaxf(mt[i], __shfl_xor(mt[i], d));
        }

        float mnew[4], corr[4], csum[4];
#pragma unroll
        for (int i = 0; i < 4; ++i) {
            mnew[i] = fmaxf(m_run[i], mt[i]);
            corr[i] = __expf(m_run[i] - mnew[i]);   // exp(-inf)=0 on first chunk
            csum[i] = 0.f;
        }
        float ev[4][4];
#pragma unroll
        for (int t = 0; t < 4; ++t) {
#pragma unroll
            for (int i = 0; i < 4; ++i) {
                ev[t][i] = __expf(sv[t][i] - mnew[i]);  // masked -> exp(-inf)=0
                csum[i] += ev[t][i];
            }
        }
#pragma unroll
        for (int d = 1; d < 16; d <<= 1) {
#pragma unroll
            for (int i = 0; i < 4; ++i) csum[i] += __shfl_xor(csum[i], d);
        }
#pragma unroll
        for (int i = 0; i < 4; ++i) {
            s_run[i] = s_run[i] * corr[i] + csum[i];
            m_run[i] = mnew[i];
        }

        // write unnormalized exp values (attn region used as scratch)
#pragma unroll
        for (int t = 0; t < 4; ++t) {
            const int kgl = kc + t * 16 + r16;
#pragma unroll
            for (int i = 0; i < 4; ++i)
                abase[(size_t)(qrow_base + i) * T_S + kgl] = ev[t][i];
        }
        if (r16 == 0) {
#pragma unroll
            for (int i = 0; i < 4; ++i) mW[w * 16 + kg * 4 + i][cc] = mnew[i];
        }
    }

    if (r16 == 0) {
#pragma unroll
        for (int i = 0; i < 4; ++i) {
            const int r = w * 16 + kg * 4 + i;
            mF[r] = m_run[i];
            iS[r] = 1.0f / s_run[i];
        }
    }

    // ================= pass 2: normalize P, write it, y = P·V =================
    f32x4 accy[4];
    {
        const f32x4 z = {0.f, 0.f, 0.f, 0.f};
#pragma unroll
        for (int t = 0; t < 4; ++t) accy[t] = z;
    }
    const int prow = w * 16 + r16;                 // A-frag q-row
    const size_t prowoff = (size_t)(q0 + prow) * T_S;

    for (int cc = 0; cc <= qb; ++cc) {
        const int kc = cc * 64;
        __syncthreads();
        // stage V chunk transposed: KV0/KV1 become Vh[d][k], Vl[d][k]
#pragma unroll
        for (int it = 0; it < 8; ++it) {
            int idx = tid + it * 256;      // 2048 = 64 d x 32 k-pairs
            int d   = idx & 63;
            int p2  = idx >> 6;
            float a = vbase[(size_t)(kc + 2 * p2) * E_D + d];
            float c = vbase[(size_t)(kc + 2 * p2 + 1) * E_D + d];
            unsigned hpack = (unsigned)bf_hi(a) | ((unsigned)bf_hi(c) << 16);
            unsigned lpack = (unsigned)bf_rne(a - bf_hi_f(a)) |
                             ((unsigned)bf_rne(c - bf_hi_f(c)) << 16);
            *(unsigned*)&KV0[d][2 * p2] = hpack;
            *(unsigned*)&KV1[d][2 * p2] = lpack;
        }
        __syncthreads();

        const float fac = __expf(mW[prow][cc] - mF[prow]) * iS[prow];
#pragma unroll
        for (int ks = 0; ks < 64; ks += 32) {
            const size_t eoff = prowoff + kc + ks + kg * 8;
            float4 e0 = *(const float4*)&abase[eoff];
            float4 e1 = *(const float4*)&abase[eoff + 4];
            float pv[8] = {e0.x * fac, e0.y * fac, e0.z * fac, e0.w * fac,
                           e1.x * fac, e1.y * fac, e1.z * fac, e1.w * fac};
            float4 w0 = {pv[0], pv[1], pv[2], pv[3]};
            float4 w1 = {pv[4], pv[5], pv[6], pv[7]};
            *(float4*)&abase[eoff]     = w0;   // final softmax weights
            *(float4*)&abase[eoff + 4] = w1;

            bf16x8 ph, pl;
#pragma unroll
            for (int j = 0; j < 8; ++j) {
                ((unsigned short*)&ph)[j] = bf_hi(pv[j]);
                ((unsigned short*)&pl)[j] = bf_rne(pv[j] - bf_hi_f(pv[j]));
            }
#pragma unroll
            for (int t = 0; t < 4; ++t) {
                const int vr = t * 16 + r16;
                const bf16x8 vh = *(const bf16x8*)&KV0[vr][ks + kg * 8];
                const bf16x8 vl = *(const bf16x8*)&KV1[vr][ks + kg * 8];
                accy[t] = __builtin_amdgcn_mfma_f32_16x16x32_bf16(ph, vh, accy[t], 0, 0, 0);
                accy[t] = __builtin_amdgcn_mfma_f32_16x16x32_bf16(ph, vl, accy[t], 0, 0, 0);
                accy[t] = __builtin_amdgcn_mfma_f32_16x16x32_bf16(pl, vh, accy[t], 0, 0, 0);
            }
        }
    }

    // ---- write y tile ----
#pragma unroll
    for (int t = 0; t < 4; ++t) {
#pragma unroll
        for (int i = 0; i < 4; ++i) {
            const int qg = q0 + w * 16 + kg * 4 + i;
            const int d  = t * 16 + r16;
            Yg[((size_t)n * T_S + qg) * E_D + h * H_D + d] = accy[t][i];
        }
    }

    // ---- zero-fill strictly-upper region ----
    const int kz0 = (qb + 1) * 64;
    for (int r = 0; r < Q_B; ++r) {
        for (int c = kz0 + tid * 4; c < T_S; c += 1024) {
            const float4 z = {0.f, 0.f, 0.f, 0.f};
            *(float4*)&abase[(size_t)(q0 + r) * T_S + c] = z;
        }
    }
}

extern "C" void kernel_launch(void* const* d_in, const int* in_sizes, int n_in,
                              void* d_out, int out_size, void* d_ws, size_t ws_size,
                              hipStream_t stream) {
    const float* q = (const float*)d_in[0];
    const float* k = (const float*)d_in[1];
    const float* v = (const float*)d_in[2];
    float* y    = (float*)d_out;
    float* attn = y + (size_t)N_B * T_S * E_D;   // outputs concatenated: y then attn_weights

    dim3 grid(N_B * N_H * (T_S / Q_B));          // 2048 blocks
    dim3 block(256);
    hipLaunchKernelGGL(mha_fused_kernel, grid, block, 0, stream, q, k, v, y, attn);
}